// Round 1
// baseline (139.215 us; speedup 1.0000x reference)
//
#include <hip/hip_runtime.h>
#include <hip/hip_bf16.h>
#include <cstdint>

typedef __attribute__((ext_vector_type(4))) float f32x4;
typedef __attribute__((ext_vector_type(8))) short s16x8;

#define NB   32
#define NL   2048
#define NH   512
#define NM   (NB * NL)          // 65536 rows
#define SCALE 0.04419417382415922f  // 1/sqrt(512)
#define LDST 40                 // padded LDS row stride (ushorts): 32 + 8

__device__ __forceinline__ ushort f2bf(float f) {
    union { float f; unsigned u; } a; a.f = f;
    unsigned u = a.u;
    unsigned r = (u + 0x7FFFu + ((u >> 16) & 1u)) >> 16;  // RNE
    return (ushort)r;
}

// ---- convert W_ref (512x512 f32) to bf16 ----
__global__ __launch_bounds__(256) void k_convW(const float* __restrict__ W,
                                               ushort* __restrict__ Wb) {
    int i = blockIdx.x * 256 + threadIdx.x;        // 32768 threads, 8 f32 each
    const float4* s = (const float4*)W;
    float4 a = s[2 * i], c = s[2 * i + 1];
    union { ushort u[8]; int4 v; } p;
    p.u[0] = f2bf(a.x); p.u[1] = f2bf(a.y); p.u[2] = f2bf(a.z); p.u[3] = f2bf(a.w);
    p.u[4] = f2bf(c.x); p.u[5] = f2bf(c.y); p.u[6] = f2bf(c.z); p.u[7] = f2bf(c.w);
    ((int4*)Wb)[i] = p.v;
}

// ---- eq[b][o] = dot(query[b,:], W_q[o,:]) ----
__global__ __launch_bounds__(512) void k_eq(const float* __restrict__ query,
                                            const float* __restrict__ Wq,
                                            float* __restrict__ eq) {
    int b = blockIdx.x;
    int o = threadIdx.x;
    __shared__ float q[NH];
    q[o] = query[b * NH + o];
    __syncthreads();
    const float4* w = (const float4*)(Wq + (size_t)o * NH);
    float acc = 0.f;
#pragma unroll 4
    for (int i = 0; i < NH / 4; ++i) {
        float4 x = w[i];
        acc += q[4 * i] * x.x + q[4 * i + 1] * x.y + q[4 * i + 2] * x.z + q[4 * i + 3] * x.w;
    }
    eq[b * NH + o] = acc;
}

// ---- fused GEMM (ref @ W_ref^T) + tanh + v-dot partial ----
// grid 2048 blocks x 256 thr. Tile 128x128, K-step 32, 4 waves (2x2), 4x4 frags/wave.
__global__ __launch_bounds__(256) void k_gemm(const float* __restrict__ ref,
                                              const ushort* __restrict__ Wb,
                                              const float* __restrict__ eq,
                                              const float* __restrict__ v,
                                              float* __restrict__ part) {
    __shared__ ushort As[128 * LDST];
    __shared__ ushort Bs[128 * LDST];

    int tid = threadIdx.x;
    int lane = tid & 63, wid = tid >> 6;
    int wr = wid >> 1, wc = wid & 1;

    // XCD-aware swizzle: the 4 n-tiles of one m-tile land on the same XCD
    int phys = blockIdx.x;
    int xcd = phys & 7, slot = phys >> 3;         // 8 XCDs x 256 slots
    int mt = xcd * 64 + (slot >> 2);              // 512 m-tiles
    int nt = slot & 3;                            // 4 n-tiles
    int m0 = mt * 128, n0 = nt * 128;
    int b = mt >> 4;                              // 16 m-tiles per batch

    f32x4 acc[4][4];
#pragma unroll
    for (int i = 0; i < 4; ++i)
#pragma unroll
        for (int j = 0; j < 4; ++j) acc[i][j] = (f32x4)(0.f);

    int srow = tid >> 1, sks = (tid & 1) * 16;
    const float*  asrc = ref + (size_t)(m0 + srow) * NH + sks;
    const ushort* bsrc = Wb + (size_t)(n0 + srow) * NH + sks;
    int awr = srow * LDST + sks;

    int lr = lane & 15, kq = lane >> 4;
    int aoff[4], boff[4];
#pragma unroll
    for (int f = 0; f < 4; ++f) {
        aoff[f] = (wr * 64 + f * 16 + lr) * LDST + kq * 8;
        boff[f] = (wc * 64 + f * 16 + lr) * LDST + kq * 8;
    }

    for (int kt = 0; kt < 16; ++kt) {
        __syncthreads();
        {   // stage A: f32 -> bf16 on the fly (16 floats / thread)
            const float* s = asrc + kt * 32;
            float4 f0 = *(const float4*)(s);
            float4 f1 = *(const float4*)(s + 4);
            float4 f2 = *(const float4*)(s + 8);
            float4 f3 = *(const float4*)(s + 12);
            union { ushort u[8]; int4 v; } p0, p1;
            p0.u[0] = f2bf(f0.x); p0.u[1] = f2bf(f0.y); p0.u[2] = f2bf(f0.z); p0.u[3] = f2bf(f0.w);
            p0.u[4] = f2bf(f1.x); p0.u[5] = f2bf(f1.y); p0.u[6] = f2bf(f1.z); p0.u[7] = f2bf(f1.w);
            p1.u[0] = f2bf(f2.x); p1.u[1] = f2bf(f2.y); p1.u[2] = f2bf(f2.z); p1.u[3] = f2bf(f2.w);
            p1.u[4] = f2bf(f3.x); p1.u[5] = f2bf(f3.y); p1.u[6] = f2bf(f3.z); p1.u[7] = f2bf(f3.w);
            *(int4*)&As[awr] = p0.v;
            *(int4*)&As[awr + 8] = p1.v;
            // stage B (already bf16): 16 bf16 / thread
            const int4* bs = (const int4*)(bsrc + kt * 32);
            *(int4*)&Bs[awr] = bs[0];
            *(int4*)&Bs[awr + 8] = bs[1];
        }
        __syncthreads();
        s16x8 af[4], bf[4];
#pragma unroll
        for (int f = 0; f < 4; ++f) af[f] = *(const s16x8*)&As[aoff[f]];
#pragma unroll
        for (int f = 0; f < 4; ++f) bf[f] = *(const s16x8*)&Bs[boff[f]];
#pragma unroll
        for (int fr = 0; fr < 4; ++fr)
#pragma unroll
            for (int fc = 0; fc < 4; ++fc)
                acc[fr][fc] = __builtin_amdgcn_mfma_f32_16x16x32_bf16(
                    af[fr], bf[fc], acc[fr][fc], 0, 0, 0);
    }

    // epilogue: partial score = sum_{o in tile} v[o]*tanh(e + eq[b][o])
    const float* eqb = eq + b * NH;
    float vv[4], ee[4];
#pragma unroll
    for (int fc = 0; fc < 4; ++fc) {
        int c = n0 + wc * 64 + fc * 16 + lr;
        vv[fc] = v[c];
        ee[fc] = eqb[c];
    }
#pragma unroll
    for (int fr = 0; fr < 4; ++fr) {
#pragma unroll
        for (int reg = 0; reg < 4; ++reg) {
            float s = 0.f;
#pragma unroll
            for (int fc = 0; fc < 4; ++fc) {
                float x = acc[fr][fc][reg] + ee[fc];
                float t = 1.f - 2.f / (__expf(2.f * x) + 1.f);  // tanh
                s += vv[fc] * t;
            }
            s += __shfl_xor(s, 1);
            s += __shfl_xor(s, 2);
            s += __shfl_xor(s, 4);
            s += __shfl_xor(s, 8);
            if (lr == 0) {
                int row = wr * 64 + fr * 16 + kq * 4 + reg;
                part[(size_t)nt * NM + m0 + row] = s;
            }
        }
    }
}

// ---- per-batch: combine partials, mask, write scores, softmax -> attn ----
__global__ __launch_bounds__(256) void k_softmax(const float* __restrict__ part,
                                                 const int* __restrict__ mask,
                                                 float* __restrict__ out_sc,
                                                 float* __restrict__ attn) {
    int b = blockIdx.x;
    int tid = threadIdx.x;
    int lane = tid & 63, wid = tid >> 6;
    __shared__ float red[4];
    float sc[8];
    float mx = -3.4e38f;
#pragma unroll
    for (int i = 0; i < 8; ++i) {
        int m = b * NL + i * 256 + tid;
        float s = (part[m] + part[NM + m] + part[2 * NM + m] + part[3 * NM + m]) * SCALE;
        if (mask[m] != 0) s = -1e9f;
        out_sc[m] = s;
        sc[i] = s;
        mx = fmaxf(mx, s);
    }
#pragma unroll
    for (int o = 32; o >= 1; o >>= 1) mx = fmaxf(mx, __shfl_xor(mx, o));
    if (lane == 0) red[wid] = mx;
    __syncthreads();
    mx = fmaxf(fmaxf(red[0], red[1]), fmaxf(red[2], red[3]));
    __syncthreads();
    float ls = 0.f;
#pragma unroll
    for (int i = 0; i < 8; ++i) {
        float e = __expf(sc[i] - mx);
        sc[i] = e;
        ls += e;
    }
#pragma unroll
    for (int o = 32; o >= 1; o >>= 1) ls += __shfl_xor(ls, o);
    if (lane == 0) red[wid] = ls;
    __syncthreads();
    float inv = 1.f / (red[0] + red[1] + red[2] + red[3]);
#pragma unroll
    for (int i = 0; i < 8; ++i) attn[b * NL + i * 256 + tid] = sc[i] * inv;
}

// ---- glimpse partials: grid (16 splits, 32 batches) ----
__global__ __launch_bounds__(256) void k_glp(const float* __restrict__ ref,
                                             const float* __restrict__ attn,
                                             float* __restrict__ glp) {
    int sp = blockIdx.x, b = blockIdx.y;
    int tid = threadIdx.x;
    const float* attb = attn + b * NL + sp * 128;
    float2 acc = make_float2(0.f, 0.f);
#pragma unroll 4
    for (int l = 0; l < 128; ++l) {
        float a = attb[l];
        const float2* row = (const float2*)(ref + (size_t)(b * NL + sp * 128 + l) * NH);
        float2 r = row[tid];
        acc.x += a * r.x;
        acc.y += a * r.y;
    }
    ((float2*)(glp + (size_t)(sp * NB + b) * NH))[tid] = acc;
}

// ---- reduce glimpse partials ----
__global__ __launch_bounds__(256) void k_gred(const float* __restrict__ glp,
                                              float* __restrict__ out_gl) {
    int idx = blockIdx.x * 256 + threadIdx.x;   // 16384 = B*H
    float s = 0.f;
#pragma unroll
    for (int sp = 0; sp < 16; ++sp) s += glp[sp * (NB * NH) + idx];
    out_gl[idx] = s;
}

extern "C" void kernel_launch(void* const* d_in, const int* in_sizes, int n_in,
                              void* d_out, int out_size, void* d_ws, size_t ws_size,
                              hipStream_t stream) {
    const float* query = (const float*)d_in[0];
    const float* ref   = (const float*)d_in[1];
    const int*   mask  = (const int*)d_in[2];
    const float* W_ref = (const float*)d_in[3];
    const float* W_q   = (const float*)d_in[4];
    const float* v     = (const float*)d_in[5];

    float* out_gl = (float*)d_out;              // 32*512
    float* out_sc = out_gl + NB * NH;           // 32*2048

    char* w = (char*)d_ws;
    ushort* wW  = (ushort*)w;                   // 512*512*2  = 524288 B
    float* eq   = (float*)(w + 524288);         // 32*512*4   = 65536 B
    float* part = (float*)(w + 589824);         // 4*65536*4  = 1048576 B
    float* attn = (float*)(w + 1638400);        // 65536*4    = 262144 B
    float* glp  = (float*)(w + 1900544);        // 16*32*512*4= 1048576 B

    k_convW<<<128, 256, 0, stream>>>(W_ref, wW);
    k_eq<<<NB, 512, 0, stream>>>(query, W_q, eq);
    k_gemm<<<2048, 256, 0, stream>>>(ref, wW, eq, v, part);
    k_softmax<<<NB, 256, 0, stream>>>(part, mask, out_sc, attn);
    k_glp<<<dim3(16, NB), 256, 0, stream>>>(ref, attn, glp);
    k_gred<<<64, 256, 0, stream>>>(glp, out_gl);
}

// Round 2
// 128.561 us; speedup vs baseline: 1.0829x; 1.0829x over previous
//
#include <hip/hip_runtime.h>
#include <hip/hip_bf16.h>
#include <cstdint>

typedef __attribute__((ext_vector_type(4))) float f32x4;
typedef __attribute__((ext_vector_type(8))) short s16x8;

#define NB   32
#define NL   2048
#define NH   512
#define NM   (NB * NL)          // 65536 rows
#define SCALE 0.04419417382415922f  // 1/sqrt(512)
#define LDST 36                 // padded LDS row stride (ushorts): 32 + 4 -> 18 dwords, gcd(18,32)=2

__device__ __forceinline__ ushort f2bf(float f) {
    __hip_bfloat16 b = __float2bfloat16(f);   // compiler fuses pairs into v_cvt_pk_bf16_f32
    return *reinterpret_cast<ushort*>(&b);
}

// ---- convert W_ref (512x512 f32) to bf16 ----
__global__ __launch_bounds__(256) void k_convW(const float* __restrict__ W,
                                               ushort* __restrict__ Wb) {
    int i = blockIdx.x * 256 + threadIdx.x;        // 32768 threads, 8 f32 each
    const float4* s = (const float4*)W;
    float4 a = s[2 * i], c = s[2 * i + 1];
    union { ushort u[8]; int4 v; } p;
    p.u[0] = f2bf(a.x); p.u[1] = f2bf(a.y); p.u[2] = f2bf(a.z); p.u[3] = f2bf(a.w);
    p.u[4] = f2bf(c.x); p.u[5] = f2bf(c.y); p.u[6] = f2bf(c.z); p.u[7] = f2bf(c.w);
    ((int4*)Wb)[i] = p.v;
}

// ---- eq[b][o] = dot(query[b,:], W_q[o,:]) ----
__global__ __launch_bounds__(512) void k_eq(const float* __restrict__ query,
                                            const float* __restrict__ Wq,
                                            float* __restrict__ eq) {
    int b = blockIdx.x;
    int o = threadIdx.x;
    __shared__ float q[NH];
    q[o] = query[b * NH + o];
    __syncthreads();
    const float4* w = (const float4*)(Wq + (size_t)o * NH);
    float acc = 0.f;
#pragma unroll 4
    for (int i = 0; i < NH / 4; ++i) {
        float4 x = w[i];
        acc += q[4 * i] * x.x + q[4 * i + 1] * x.y + q[4 * i + 2] * x.z + q[4 * i + 3] * x.w;
    }
    eq[b * NH + o] = acc;
}

// ---- fused GEMM (ref @ W_ref^T) + tanh + v-dot partial ----
// grid 2048 blocks x 256 thr. Tile 128x128, K-step 32, 4 waves (2x2), 4x4 frags/wave.
// Register-prefetch pipeline: loads for kt+1 issue before MFMA of kt.
__global__ __launch_bounds__(256) void k_gemm(const float* __restrict__ ref,
                                              const ushort* __restrict__ Wb,
                                              const float* __restrict__ eq,
                                              const float* __restrict__ v,
                                              float* __restrict__ part) {
    __shared__ ushort As[128 * LDST];
    __shared__ ushort Bs[128 * LDST];

    int tid = threadIdx.x;
    int lane = tid & 63, wid = tid >> 6;
    int wr = wid >> 1, wc = wid & 1;

    // XCD-aware swizzle: the 4 n-tiles of one m-tile land on the same XCD
    int phys = blockIdx.x;
    int xcd = phys & 7, slot = phys >> 3;         // 8 XCDs x 256 slots
    int mt = xcd * 64 + (slot >> 2);              // 512 m-tiles
    int nt = slot & 3;                            // 4 n-tiles
    int m0 = mt * 128, n0 = nt * 128;
    int b = mt >> 4;                              // 16 m-tiles per batch

    f32x4 acc[4][4];
#pragma unroll
    for (int i = 0; i < 4; ++i)
#pragma unroll
        for (int j = 0; j < 4; ++j) acc[i][j] = (f32x4)(0.f);

    int srow = tid >> 1, sks = (tid & 1) * 16;    // row 0..127, 16-elem half
    const float*  asrc = ref + (size_t)(m0 + srow) * NH + sks;
    const ushort* bsrc = Wb + (size_t)(n0 + srow) * NH + sks;
    int awr = srow * LDST + sks;

    int lr = lane & 15, kq = lane >> 4;
    int aoff[4], boff[4];
#pragma unroll
    for (int f = 0; f < 4; ++f) {
        aoff[f] = (wr * 64 + f * 16 + lr) * LDST + kq * 8;
        boff[f] = (wc * 64 + f * 16 + lr) * LDST + kq * 8;
    }

    // prefetch registers
    float4 pa0, pa1, pa2, pa3;
    int4 pb0, pb1;
    {   // preload kt=0
        const float* s = asrc;
        pa0 = *(const float4*)(s);
        pa1 = *(const float4*)(s + 4);
        pa2 = *(const float4*)(s + 8);
        pa3 = *(const float4*)(s + 12);
        const int4* bs = (const int4*)(bsrc);
        pb0 = bs[0];
        pb1 = bs[1];
    }

    for (int kt = 0; kt < 16; ++kt) {
        // pack + write LDS from prefetch regs
        union { ushort u[8]; int4 v; } p0, p1;
        p0.u[0] = f2bf(pa0.x); p0.u[1] = f2bf(pa0.y); p0.u[2] = f2bf(pa0.z); p0.u[3] = f2bf(pa0.w);
        p0.u[4] = f2bf(pa1.x); p0.u[5] = f2bf(pa1.y); p0.u[6] = f2bf(pa1.z); p0.u[7] = f2bf(pa1.w);
        p1.u[0] = f2bf(pa2.x); p1.u[1] = f2bf(pa2.y); p1.u[2] = f2bf(pa2.z); p1.u[3] = f2bf(pa2.w);
        p1.u[4] = f2bf(pa3.x); p1.u[5] = f2bf(pa3.y); p1.u[6] = f2bf(pa3.z); p1.u[7] = f2bf(pa3.w);
        *(int4*)&As[awr] = p0.v;
        *(int4*)&As[awr + 8] = p1.v;
        *(int4*)&Bs[awr] = pb0;
        *(int4*)&Bs[awr + 8] = pb1;
        __syncthreads();

        // issue next tile's global loads (consumed next iteration)
        if (kt < 15) {
            const float* s = asrc + (kt + 1) * 32;
            pa0 = *(const float4*)(s);
            pa1 = *(const float4*)(s + 4);
            pa2 = *(const float4*)(s + 8);
            pa3 = *(const float4*)(s + 12);
            const int4* bs = (const int4*)(bsrc + (kt + 1) * 32);
            pb0 = bs[0];
            pb1 = bs[1];
        }

        // read fragments, then barrier (other waves may start staging while we MFMA)
        s16x8 af[4], bf[4];
#pragma unroll
        for (int f = 0; f < 4; ++f) af[f] = *(const s16x8*)&As[aoff[f]];
#pragma unroll
        for (int f = 0; f < 4; ++f) bf[f] = *(const s16x8*)&Bs[boff[f]];
        __syncthreads();

#pragma unroll
        for (int fr = 0; fr < 4; ++fr)
#pragma unroll
            for (int fc = 0; fc < 4; ++fc)
                acc[fr][fc] = __builtin_amdgcn_mfma_f32_16x16x32_bf16(
                    af[fr], bf[fc], acc[fr][fc], 0, 0, 0);
    }

    // epilogue: partial score = sum_{o in tile} v[o]*tanh(e + eq[b][o])
    const float* eqb = eq + b * NH;
    float vv[4], ee[4];
#pragma unroll
    for (int fc = 0; fc < 4; ++fc) {
        int c = n0 + wc * 64 + fc * 16 + lr;
        vv[fc] = v[c];
        ee[fc] = eqb[c];
    }
#pragma unroll
    for (int fr = 0; fr < 4; ++fr) {
#pragma unroll
        for (int reg = 0; reg < 4; ++reg) {
            float s = 0.f;
#pragma unroll
            for (int fc = 0; fc < 4; ++fc) {
                float x = acc[fr][fc][reg] + ee[fc];
                float t = 1.f - 2.f / (__expf(2.f * x) + 1.f);  // tanh
                s += vv[fc] * t;
            }
            s += __shfl_xor(s, 1);
            s += __shfl_xor(s, 2);
            s += __shfl_xor(s, 4);
            s += __shfl_xor(s, 8);
            if (lr == 0) {
                int row = wr * 64 + fr * 16 + kq * 4 + reg;
                part[(size_t)nt * NM + m0 + row] = s;
            }
        }
    }
}

// ---- per-batch: combine partials, mask, write scores, softmax -> attn ----
__global__ __launch_bounds__(256) void k_softmax(const float* __restrict__ part,
                                                 const int* __restrict__ mask,
                                                 float* __restrict__ out_sc,
                                                 float* __restrict__ attn) {
    int b = blockIdx.x;
    int tid = threadIdx.x;
    int lane = tid & 63, wid = tid >> 6;
    __shared__ float red[4];
    float sc[8];
    float mx = -3.4e38f;
#pragma unroll
    for (int i = 0; i < 8; ++i) {
        int m = b * NL + i * 256 + tid;
        float s = (part[m] + part[NM + m] + part[2 * NM + m] + part[3 * NM + m]) * SCALE;
        if (mask[m] != 0) s = -1e9f;
        out_sc[m] = s;
        sc[i] = s;
        mx = fmaxf(mx, s);
    }
#pragma unroll
    for (int o = 32; o >= 1; o >>= 1) mx = fmaxf(mx, __shfl_xor(mx, o));
    if (lane == 0) red[wid] = mx;
    __syncthreads();
    mx = fmaxf(fmaxf(red[0], red[1]), fmaxf(red[2], red[3]));
    __syncthreads();
    float ls = 0.f;
#pragma unroll
    for (int i = 0; i < 8; ++i) {
        float e = __expf(sc[i] - mx);
        sc[i] = e;
        ls += e;
    }
#pragma unroll
    for (int o = 32; o >= 1; o >>= 1) ls += __shfl_xor(ls, o);
    if (lane == 0) red[wid] = ls;
    __syncthreads();
    float inv = 1.f / (red[0] + red[1] + red[2] + red[3]);
#pragma unroll
    for (int i = 0; i < 8; ++i) attn[b * NL + i * 256 + tid] = sc[i] * inv;
}

// ---- glimpse partials: grid (16 splits, 32 batches) ----
__global__ __launch_bounds__(256) void k_glp(const float* __restrict__ ref,
                                             const float* __restrict__ attn,
                                             float* __restrict__ glp) {
    int sp = blockIdx.x, b = blockIdx.y;
    int tid = threadIdx.x;
    const float* attb = attn + b * NL + sp * 128;
    float2 acc = make_float2(0.f, 0.f);
#pragma unroll 4
    for (int l = 0; l < 128; ++l) {
        float a = attb[l];
        const float2* row = (const float2*)(ref + (size_t)(b * NL + sp * 128 + l) * NH);
        float2 r = row[tid];
        acc.x += a * r.x;
        acc.y += a * r.y;
    }
    ((float2*)(glp + (size_t)(sp * NB + b) * NH))[tid] = acc;
}

// ---- reduce glimpse partials ----
__global__ __launch_bounds__(256) void k_gred(const float* __restrict__ glp,
                                              float* __restrict__ out_gl) {
    int idx = blockIdx.x * 256 + threadIdx.x;   // 16384 = B*H
    float s = 0.f;
#pragma unroll
    for (int sp = 0; sp < 16; ++sp) s += glp[sp * (NB * NH) + idx];
    out_gl[idx] = s;
}

extern "C" void kernel_launch(void* const* d_in, const int* in_sizes, int n_in,
                              void* d_out, int out_size, void* d_ws, size_t ws_size,
                              hipStream_t stream) {
    const float* query = (const float*)d_in[0];
    const float* ref   = (const float*)d_in[1];
    const int*   mask  = (const int*)d_in[2];
    const float* W_ref = (const float*)d_in[3];
    const float* W_q   = (const float*)d_in[4];
    const float* v     = (const float*)d_in[5];

    float* out_gl = (float*)d_out;              // 32*512
    float* out_sc = out_gl + NB * NH;           // 32*2048

    char* w = (char*)d_ws;
    ushort* wW  = (ushort*)w;                   // 512*512*2  = 524288 B
    float* eq   = (float*)(w + 524288);         // 32*512*4   = 65536 B
    float* part = (float*)(w + 589824);         // 4*65536*4  = 1048576 B
    float* attn = (float*)(w + 1638400);        // 65536*4    = 262144 B
    float* glp  = (float*)(w + 1900544);        // 16*32*512*4= 1048576 B

    k_convW<<<128, 256, 0, stream>>>(W_ref, wW);
    k_eq<<<NB, 512, 0, stream>>>(query, W_q, eq);
    k_gemm<<<2048, 256, 0, stream>>>(ref, wW, eq, v, part);
    k_softmax<<<NB, 256, 0, stream>>>(part, mask, out_sc, attn);
    k_glp<<<dim3(16, NB), 256, 0, stream>>>(ref, attn, glp);
    k_gred<<<64, 256, 0, stream>>>(glp, out_gl);
}